// Round 1
// baseline (160.768 us; speedup 1.0000x reference)
//
#include <hip/hip_runtime.h>
#include <stdint.h>

// random_masking: out = input, except channels {0,10,...,90} of each batch are
// replaced with jax.random.normal(jax.random.key(1), (4, 10, 512*512)).
// We replicate JAX's partitionable Threefry-2x32 + XLA erfinv exactly.

__device__ __forceinline__ uint32_t rotl32(uint32_t v, int r) {
    return (v << r) | (v >> (32 - r));
}

// Threefry-2x32, key = (0, 1)  [jax.random.key(1): k1=seed>>32=0, k2=seed&0xffffffff=1]
__device__ __forceinline__ void threefry2x32_key01(uint32_t x0, uint32_t x1,
                                                   uint32_t& o0, uint32_t& o1) {
    const uint32_t ks0 = 0u;
    const uint32_t ks1 = 1u;
    const uint32_t ks2 = 0x1BD11BDAu ^ ks0 ^ ks1;  // 0x1BD11BDB
    x0 += ks0; x1 += ks1;
#define TF_R(r) { x0 += x1; x1 = rotl32(x1, (r)); x1 ^= x0; }
    TF_R(13) TF_R(15) TF_R(26) TF_R(6)
    x0 += ks1; x1 += ks2 + 1u;
    TF_R(17) TF_R(29) TF_R(16) TF_R(24)
    x0 += ks2; x1 += ks0 + 2u;
    TF_R(13) TF_R(15) TF_R(26) TF_R(6)
    x0 += ks0; x1 += ks1 + 3u;
    TF_R(17) TF_R(29) TF_R(16) TF_R(24)
    x0 += ks1; x1 += ks2 + 4u;
    TF_R(13) TF_R(15) TF_R(26) TF_R(6)
    x0 += ks2; x1 += ks0 + 5u;
#undef TF_R
    o0 = x0; o1 = x1;
}

// XLA f32 ErfInv (Giles polynomial) — identical coefficients to xla/client/lib/math.cc
__device__ __forceinline__ float erfinv_xla_f32(float x) {
    float w = -log1pf(-x * x);
    float p;
    if (w < 5.0f) {
        w = w - 2.5f;
        p = 2.81022636e-08f;
        p = fmaf(p, w, 3.43273939e-07f);
        p = fmaf(p, w, -3.5233877e-06f);
        p = fmaf(p, w, -4.39150654e-06f);
        p = fmaf(p, w, 0.00021858087f);
        p = fmaf(p, w, -0.00125372503f);
        p = fmaf(p, w, -0.00417768164f);
        p = fmaf(p, w, 0.246640727f);
        p = fmaf(p, w, 1.50140941f);
    } else {
        w = sqrtf(w) - 3.0f;
        p = -0.000200214257f;
        p = fmaf(p, w, 0.000100950558f);
        p = fmaf(p, w, 0.00134934322f);
        p = fmaf(p, w, -0.00367342844f);
        p = fmaf(p, w, 0.00573950773f);
        p = fmaf(p, w, -0.0076224613f);
        p = fmaf(p, w, 0.00943887047f);
        p = fmaf(p, w, 1.00167406f);
        p = fmaf(p, w, 2.83297682f);
    }
    return p * x;
}

// bits -> uniform(nextafter(-1,0), 1) -> sqrt(2)*erfinv(u), matching JAX normal()
__device__ __forceinline__ float bits_to_normal(uint32_t bits) {
    float f = __uint_as_float((bits >> 9) | 0x3F800000u) - 1.0f;  // [0, 1)
    const float lo = __uint_as_float(0xBF7FFFFFu);                // nextafter(-1f, 0)
    // floats * (1.0 - lo) + lo ; (1.0 - lo) rounds to exactly 2.0f in f32, and the
    // sum f*2+lo is exactly representable for every f, so this matches JAX bit-exact.
    float u = f * 2.0f + lo;
    u = fmaxf(lo, u);  // lax.max(minval, ...) — no-op but keep semantics
    const float sqrt2 = __uint_as_float(0x3FB504F3u);             // float32(sqrt(2))
    return sqrt2 * erfinv_xla_f32(u);
}

// Geometry: (4, 100, 512, 512) f32. 512*512 = 262144 elems = 65536 float4 per channel.
// Noise channels: c % 10 == 0  (sel = [0,10,...,90]); noise array (4, 10, 262144),
// flat index j = (b*10 + c/10)*262144 + d.
constexpr uint32_t CH4    = 65536u;      // float4 per channel
constexpr uint32_t TOTAL4 = 4u * 100u * CH4;  // 26,214,400

__global__ __launch_bounds__(256) void random_masking_kernel(
        const float4* __restrict__ in, float4* __restrict__ out) {
    uint32_t stride = gridDim.x * blockDim.x;
    for (uint32_t i = blockIdx.x * blockDim.x + threadIdx.x; i < TOTAL4; i += stride) {
        uint32_t cb = i >> 16;          // b*100 + c   (wave-uniform: 65536 % 64 == 0)
        uint32_t c  = cb % 100u;
        if (c % 10u != 0u) {
            out[i] = in[i];             // plain copy channel
        } else {
            uint32_t b = cb / 100u;
            uint32_t s = c / 10u;
            // noise flat element index of first lane-element
            uint32_t j = ((b * 10u + s) << 18) | ((i & 65535u) << 2);
            float4 o;
            float* po = reinterpret_cast<float*>(&o);
#pragma unroll
            for (int e = 0; e < 4; ++e) {
                // partitionable threefry: counter = uint64(j+e) -> (hi,lo)=(0, j+e),
                // 32-bit draw = y0 ^ y1
                uint32_t y0, y1;
                threefry2x32_key01(0u, j + (uint32_t)e, y0, y1);
                po[e] = bits_to_normal(y0 ^ y1);
            }
            out[i] = o;
        }
    }
}

extern "C" void kernel_launch(void* const* d_in, const int* in_sizes, int n_in,
                              void* d_out, int out_size, void* d_ws, size_t ws_size,
                              hipStream_t stream) {
    const float4* in = reinterpret_cast<const float4*>(d_in[0]);
    float4* out = reinterpret_cast<float4*>(d_out);
    // memory-bound: ~2048 blocks, grid-stride
    random_masking_kernel<<<2048, 256, 0, stream>>>(in, out);
}

// Round 2
// 151.459 us; speedup vs baseline: 1.0615x; 1.0615x over previous
//
#include <hip/hip_runtime.h>
#include <stdint.h>

// random_masking: out = input, except channels {0,10,...,90} of each batch are
// replaced with jax.random.normal(jax.random.key(1), (4, 10, 512*512)).
// PRNG path (verified R1, absmax 1.5e-2 vs 1.08e-1 threshold): partitionable
// Threefry-2x32 + XLA Giles erfinv. DO NOT change numerics.
//
// R2 structure: 2048-float4 tiles => block-uniform copy/noise role, 8 loads in
// flight per thread, nontemporal streaming (838 MB through 256 MB L3).

typedef float f32x4 __attribute__((ext_vector_type(4)));

__device__ __forceinline__ uint32_t rotl32(uint32_t v, int r) {
    return (v << r) | (v >> (32 - r));
}

// Threefry-2x32, key = (0, 1)  [jax.random.key(1)]
__device__ __forceinline__ void threefry2x32_key01(uint32_t x0, uint32_t x1,
                                                   uint32_t& o0, uint32_t& o1) {
    const uint32_t ks0 = 0u;
    const uint32_t ks1 = 1u;
    const uint32_t ks2 = 0x1BD11BDAu ^ ks0 ^ ks1;  // 0x1BD11BDB
    x0 += ks0; x1 += ks1;
#define TF_R(r) { x0 += x1; x1 = rotl32(x1, (r)); x1 ^= x0; }
    TF_R(13) TF_R(15) TF_R(26) TF_R(6)
    x0 += ks1; x1 += ks2 + 1u;
    TF_R(17) TF_R(29) TF_R(16) TF_R(24)
    x0 += ks2; x1 += ks0 + 2u;
    TF_R(13) TF_R(15) TF_R(26) TF_R(6)
    x0 += ks0; x1 += ks1 + 3u;
    TF_R(17) TF_R(29) TF_R(16) TF_R(24)
    x0 += ks1; x1 += ks2 + 4u;
    TF_R(13) TF_R(15) TF_R(26) TF_R(6)
    x0 += ks2; x1 += ks0 + 5u;
#undef TF_R
    o0 = x0; o1 = x1;
}

// XLA f32 ErfInv (Giles polynomial) — identical coefficients to xla math.cc
__device__ __forceinline__ float erfinv_xla_f32(float x) {
    float w = -log1pf(-x * x);
    float p;
    if (w < 5.0f) {
        w = w - 2.5f;
        p = 2.81022636e-08f;
        p = fmaf(p, w, 3.43273939e-07f);
        p = fmaf(p, w, -3.5233877e-06f);
        p = fmaf(p, w, -4.39150654e-06f);
        p = fmaf(p, w, 0.00021858087f);
        p = fmaf(p, w, -0.00125372503f);
        p = fmaf(p, w, -0.00417768164f);
        p = fmaf(p, w, 0.246640727f);
        p = fmaf(p, w, 1.50140941f);
    } else {
        w = sqrtf(w) - 3.0f;
        p = -0.000200214257f;
        p = fmaf(p, w, 0.000100950558f);
        p = fmaf(p, w, 0.00134934322f);
        p = fmaf(p, w, -0.00367342844f);
        p = fmaf(p, w, 0.00573950773f);
        p = fmaf(p, w, -0.0076224613f);
        p = fmaf(p, w, 0.00943887047f);
        p = fmaf(p, w, 1.00167406f);
        p = fmaf(p, w, 2.83297682f);
    }
    return p * x;
}

// bits -> uniform(nextafter(-1,0), 1) -> sqrt(2)*erfinv(u), matching JAX normal()
__device__ __forceinline__ float bits_to_normal(uint32_t bits) {
    float f = __uint_as_float((bits >> 9) | 0x3F800000u) - 1.0f;  // [0, 1)
    const float lo = __uint_as_float(0xBF7FFFFFu);                // nextafter(-1f, 0)
    float u = f * 2.0f + lo;   // exact: f*2 is a pow2 scale, sum representable
    u = fmaxf(lo, u);
    const float sqrt2 = __uint_as_float(0x3FB504F3u);             // float32(sqrt(2))
    return sqrt2 * erfinv_xla_f32(u);
}

// Geometry: (4, 100, 512, 512) f32. Channel = 65536 float4. Tile = 2048 float4
// per block => 32 tiles/channel, 400 channels => 12800 blocks, block-uniform role.
constexpr uint32_t TILE_SHIFT = 11;          // 2048 f4 / tile
constexpr uint32_t TILES_PER_CH = 32;
constexpr uint32_t NBLOCKS = 400u * TILES_PER_CH;

__global__ __launch_bounds__(256) void random_masking_kernel(
        const f32x4* __restrict__ in, f32x4* __restrict__ out) {
    const uint32_t bid  = blockIdx.x;
    const uint32_t cb   = bid >> 5;              // b*100 + c, 0..399
    const uint32_t tile = bid & (TILES_PER_CH - 1);
    const uint32_t c    = cb % 100u;
    const uint32_t base = (cb << 16) + (tile << TILE_SHIFT) + threadIdx.x;

    if (c % 10u != 0u) {
        // ---- copy block: 8 independent nontemporal float4 loads in flight ----
        f32x4 v[8];
#pragma unroll
        for (int k = 0; k < 8; ++k)
            v[k] = __builtin_nontemporal_load(in + base + k * 256);
#pragma unroll
        for (int k = 0; k < 8; ++k)
            __builtin_nontemporal_store(v[k], out + base + k * 256);
    } else {
        // ---- noise block: no input read ----
        const uint32_t b = cb / 100u;
        const uint32_t s = c / 10u;
        const uint32_t jch = (b * 10u + s) << 18;    // channel base in noise array
        const uint32_t fch = (tile << TILE_SHIFT) + threadIdx.x;
#pragma unroll
        for (int k = 0; k < 8; ++k) {
            const uint32_t j = jch + ((fch + k * 256) << 2);  // noise elem index
            f32x4 o;
#pragma unroll
            for (int e = 0; e < 4; ++e) {
                uint32_t y0, y1;
                threefry2x32_key01(0u, j + (uint32_t)e, y0, y1);
                o[e] = bits_to_normal(y0 ^ y1);
            }
            __builtin_nontemporal_store(o, out + base + k * 256);
        }
    }
}

extern "C" void kernel_launch(void* const* d_in, const int* in_sizes, int n_in,
                              void* d_out, int out_size, void* d_ws, size_t ws_size,
                              hipStream_t stream) {
    const f32x4* in = reinterpret_cast<const f32x4*>(d_in[0]);
    f32x4* out = reinterpret_cast<f32x4*>(d_out);
    random_masking_kernel<<<NBLOCKS, 256, 0, stream>>>(in, out);
}